// Round 1
// baseline (618.641 us; speedup 1.0000x reference)
//
#include <hip/hip_runtime.h>

// BTT fused MFMA kernel (round 5): de-lockstepped redesign.
//
// out[b, y*64+i] = bias[y*64+i]
//   + sum_{j,a} ( sum_u X[b,j*64+u] * core0[(j*64+u)*256 + i*4+a] )
//               * core1[(j*64+y)*256 + i*4 + a]
//
// Structure per block (b-tile 64, i-tile 8), loop over 8 j-groups g:
//   stage 1: wave w owns j = g*8+w. A (X) and B (core0) MFMA fragments are
//            loaded DIRECTLY global->regs (disjoint per wave, no LDS, no
//            barrier). 16 MFMAs/wave -> z1 k-slice (k = w*4+a) into LDS.
//   C1 tile: cooperative global->reg prefetch (issued at top of g, latency
//            hidden under stage 1), converted + stored to LDS before barrier.
//   barrier; stage 2: 24 ds_read_b128 + 16 MFMAs per wave into acc; barrier.
// => 2 barriers per g (16/block) instead of 160/block.
//
// LDS: two regions of 64 rows x 512 B, XOR-swizzled byte ^= (row&7)<<4 so
// stride-512 ds_read_b128 fragment reads are <=2-way bank aliased (free).
//
// MFMA 16x16x32 bf16 layouts (HW-verified):
//   A[m][k]: m=lane&15, k=(lane>>4)*8+j ; B[k][n]: n=lane&15, k=(lane>>4)*8+j
//   D[m][n]: n=lane&15, m=(lane>>4)*4+reg

typedef unsigned short ushort_t;
typedef __attribute__((ext_vector_type(8))) short sfrag8;   // 8 bf16
typedef __attribute__((ext_vector_type(4))) float f32x4;

__device__ inline ushort_t f2bf(float f) {
    unsigned int u = __builtin_bit_cast(unsigned int, f);
    u += 0x7fffu + ((u >> 16) & 1u);   // RNE
    return (ushort_t)(u >> 16);
}

#define Z1_OFF 0        // [b(64)][512B]  byte ^= (b&7)<<4
#define C1_OFF 32768    // [y(64)][512B]  byte ^= (y&7)<<4
#define LDS_BYTES 65536

__global__ __launch_bounds__(512, 2) void btt_mfma(
    const float* __restrict__ x,      // (8192, 4096)
    const float* __restrict__ core0,  // (64*64, 256) : [(j,u)][(i,a)]
    const float* __restrict__ core1,  // (64*64, 256) : [(j,y)][(i,a)]
    const float* __restrict__ bias,   // (4096)
    float* __restrict__ out)          // (8192, 4096)
{
    __shared__ __align__(16) char smem[LDS_BYTES];

    const int t    = threadIdx.x;
    const int w    = t >> 6;          // wave 0..7
    const int lane = t & 63;
    const int quad = lane >> 4;
    const int l16  = lane & 15;

    const int b0 = blockIdx.x * 64;
    const int i0 = blockIdx.y * 8;

    const int mb = w >> 1;            // stage-2 b-tile
    const int yh = w & 1;             // stage-2 y-half

    // acc[ii][yt2]: tile (b = mb*16 + quad*4 + reg, y = (yh*2+yt2)*16 + l16, i0+ii)
    f32x4 acc[8][2];
#pragma unroll
    for (int yt2 = 0; yt2 < 2; ++yt2) {
        const int y = (yh * 2 + yt2) * 16 + l16;
#pragma unroll
        for (int ia = 0; ia < 8; ++ia) {
            const float bv = bias[y * 64 + i0 + ia];
            acc[ia][yt2] = (f32x4){bv, bv, bv, bv};
        }
    }

    // C1 cooperative staging: one (y, ii) pair per thread
    const int cy = t >> 3;            // 0..63  (y row)
    const int ci = t & 7;             // 0..7   (ii)
    const float* c1_src = core1 + (size_t)cy * 256 + (size_t)(i0 + ci) * 4;
    char* c1_dst = smem + C1_OFF + cy * 512;
    const int c1_swz = (cy & 7) << 4;

#pragma unroll 1
    for (int g = 0; g < 8; ++g) {
        const int j = g * 8 + w;

        // ---- issue C1 prefetch (global -> regs); lands during stage 1 ----
        float4 c1v[8];
#pragma unroll
        for (int c = 0; c < 8; ++c)
            c1v[c] = *(const float4*)(c1_src + (size_t)(g * 8 + c) * 16384);

        // ---- stage 1: per-wave j-column, fragments direct from global ----
        // A-frags: X rows b0..b0+63, cols j*64 + u
        sfrag8 af[4][2];
#pragma unroll
        for (int m4 = 0; m4 < 4; ++m4) {
            const float* ax = x + (size_t)(b0 + m4 * 16 + l16) * 4096 + j * 64 + quad * 8;
#pragma unroll
            for (int kh = 0; kh < 2; ++kh) {
                const float4 v0 = *(const float4*)(ax + kh * 32);
                const float4 v1 = *(const float4*)(ax + kh * 32 + 4);
                sfrag8 p;
                p[0] = (short)f2bf(v0.x); p[1] = (short)f2bf(v0.y);
                p[2] = (short)f2bf(v0.z); p[3] = (short)f2bf(v0.w);
                p[4] = (short)f2bf(v1.x); p[5] = (short)f2bf(v1.y);
                p[6] = (short)f2bf(v1.z); p[7] = (short)f2bf(v1.w);
                af[m4][kh] = p;
            }
        }

        // B-frags: core0[(j*64 + u)][i0*4 + col], k=u, n=col (transposed via
        // per-lane scalar loads; L2/L3-hot, 32 dwords/lane)
        sfrag8 bf[2][2];
#pragma unroll
        for (int nt = 0; nt < 2; ++nt) {
#pragma unroll
            for (int kh = 0; kh < 2; ++kh) {
                const float* bx = core0 + (size_t)(j * 64 + kh * 32 + quad * 8) * 256
                                + i0 * 4 + nt * 16 + l16;
                sfrag8 p;
#pragma unroll
                for (int jj = 0; jj < 8; ++jj)
                    p[jj] = (short)f2bf(bx[(size_t)jj * 256]);
                bf[nt][kh] = p;
            }
        }

        // 16 MFMAs -> z1 slice [b][ii][k = w*4 + a]
#pragma unroll
        for (int m4 = 0; m4 < 4; ++m4) {
#pragma unroll
            for (int nt = 0; nt < 2; ++nt) {
                f32x4 dd = {0.f, 0.f, 0.f, 0.f};
                dd = __builtin_amdgcn_mfma_f32_16x16x32_bf16(af[m4][0], bf[nt][0], dd, 0, 0, 0);
                dd = __builtin_amdgcn_mfma_f32_16x16x32_bf16(af[m4][1], bf[nt][1], dd, 0, 0, 0);
                const int col   = nt * 16 + l16;                       // ii*4 + a
                const int inner = (col >> 2) * 64 + (w * 4 + (col & 3)) * 2;
#pragma unroll
                for (int reg = 0; reg < 4; ++reg) {
                    const int b = m4 * 16 + quad * 4 + reg;
                    *(ushort_t*)(smem + Z1_OFF + b * 512 + (inner ^ ((b & 7) << 4))) =
                        f2bf(dd[reg]);
                }
            }
        }

        // ---- C1 regs -> LDS: [y][ii*64 + (c*4+a)*2] swizzled ----
#pragma unroll
        for (int c = 0; c < 8; ++c) {
            const ushort4 pk = make_ushort4(f2bf(c1v[c].x), f2bf(c1v[c].y),
                                            f2bf(c1v[c].z), f2bf(c1v[c].w));
            *(ushort4*)(c1_dst + ((ci * 64 + c * 8) ^ c1_swz)) = pk;
        }

        __syncthreads();   // z1 + C1 visible

        // ---- stage 2: contract K=32 (8 j x 4 a) into acc ----
        const int arow = mb * 16 + l16;
        const int aswz = (arow & 7) << 4;
#pragma unroll
        for (int ii = 0; ii < 8; ++ii) {
            const sfrag8 az = *(const sfrag8*)(smem + Z1_OFF + arow * 512
                                               + ((ii * 64 + quad * 16) ^ aswz));
#pragma unroll
            for (int yt2 = 0; yt2 < 2; ++yt2) {
                const int y16 = (yh * 2 + yt2) * 16 + l16;
                const sfrag8 bz = *(const sfrag8*)(smem + C1_OFF + y16 * 512
                                                   + ((ii * 64 + quad * 16) ^ ((y16 & 7) << 4)));
                acc[ii][yt2] = __builtin_amdgcn_mfma_f32_16x16x32_bf16(az, bz, acc[ii][yt2], 0, 0, 0);
            }
        }

        __syncthreads();   // readers done before next g's LDS writes
    }

    // ---- epilogue ----
#pragma unroll
    for (int yt2 = 0; yt2 < 2; ++yt2) {
        const int y = (yh * 2 + yt2) * 16 + l16;
#pragma unroll
        for (int reg = 0; reg < 4; ++reg) {
            const int b = mb * 16 + quad * 4 + reg;
            float* dst = out + (size_t)(b0 + b) * 4096 + y * 64 + i0;
            *(float4*)dst       = make_float4(acc[0][yt2][reg], acc[1][yt2][reg],
                                              acc[2][yt2][reg], acc[3][yt2][reg]);
            *(float4*)(dst + 4) = make_float4(acc[4][yt2][reg], acc[5][yt2][reg],
                                              acc[6][yt2][reg], acc[7][yt2][reg]);
        }
    }
}

extern "C" void kernel_launch(void* const* d_in, const int* in_sizes, int n_in,
                              void* d_out, int out_size, void* d_ws, size_t ws_size,
                              hipStream_t stream) {
    const float* x     = (const float*)d_in[0];
    const float* core0 = (const float*)d_in[1];
    const float* core1 = (const float*)d_in[2];
    const float* bias  = (const float*)d_in[3];
    float* out = (float*)d_out;

    dim3 grid(8192 / 64, 64 / 8);   // (128, 8)
    btt_mfma<<<grid, 512, 0, stream>>>(x, core0, core1, bias, out);
}

// Round 2
// 535.594 us; speedup vs baseline: 1.1551x; 1.1551x over previous
//
#include <hip/hip_runtime.h>

// BTT fused MFMA kernel (round 6): occupancy + clean-fragment redesign.
//
// out[b, y*64+i] = bias[y*64+i]
//   + sum_{j,a} ( sum_u X[b,j*64+u] * core0[(j*64+u)*256 + i*4+a] )
//               * core1[(j*64+y)*256 + i*4 + a]
//
// Prep kernels (run every launch, ~3us, into d_ws):
//   c0t[c(256)][u(4096)]      bf16 = core0[u][c]          (2 MB)
//   c1t[y(64)][i(64)][k(256)] bf16 = core1[(k>>2)*64+y][i*4+(k&3)]  (2 MB)
//
// Main kernel: 512 thr, b-tile 32, i-tile 8, grid (256, 8). Per g (8 j's):
//   stage 1 (wave w owns j=g*8+w): A=c0t frags (4x16B), B=X f32 (8xfloat4
//     + cvt). SWAPPED operands: D[col][b] so lane packs 4 consecutive 'a'
//     -> 4 ds_write_b64 to z1 (even-spread XOR swizzle, conflict-free).
//   barrier; stage 2: bz frags direct from global c1t (8x16B, L2-hot),
//     az from z1 LDS (8x ds_read_b128), 8 MFMAs into acc; barrier.
// LDS = 16 KB (z1 only). acc = 32 VGPR; total <=128 -> 2 blocks/CU.
//
// MFMA 16x16x32 bf16 layouts (HW-verified):
//   A[m][k]: m=lane&15, k=(lane>>4)*8+j ; B[k][n]: n=lane&15, k=(lane>>4)*8+j
//   D[m][n]: n=lane&15, m=(lane>>4)*4+reg

typedef unsigned short ushort_t;
typedef __attribute__((ext_vector_type(8))) short sfrag8;   // 8 bf16
typedef __attribute__((ext_vector_type(4))) float f32x4;

__device__ inline ushort_t f2bf(float f) {
    unsigned int u = __builtin_bit_cast(unsigned int, f);
    u += 0x7fffu + ((u >> 16) & 1u);   // RNE
    return (ushort_t)(u >> 16);
}

// ---------------- prep kernels ----------------
__global__ __launch_bounds__(256) void prep_c0t(const float* __restrict__ c0,
                                                ushort_t* __restrict__ c0t) {
    // c0t[c][u] = bf16(core0[u*256 + c]) ; tiled 64x64 transpose
    __shared__ float tile[64][65];
    const int t = threadIdx.x;
    const int ub = blockIdx.x * 64;   // u block: 4096/64 = 64
    const int cb = blockIdx.y * 64;   // c block: 256/64  = 4
#pragma unroll
    for (int it = 0; it < 16; ++it) {
        const int r = it * 4 + (t >> 6);
        const int c = t & 63;
        tile[r][c] = c0[(size_t)(ub + r) * 256 + cb + c];
    }
    __syncthreads();
#pragma unroll
    for (int it = 0; it < 16; ++it) {
        const int r = it * 4 + (t >> 6);   // c-local row
        const int c = t & 63;              // u-local col
        c0t[(size_t)(cb + r) * 4096 + ub + c] = f2bf(tile[c][r]);
    }
}

__global__ __launch_bounds__(256) void prep_c1t(const float* __restrict__ c1,
                                                ushort_t* __restrict__ c1t) {
    // c1t[(y*64 + i)*256 + j*4 + a] = bf16(core1[(j*64+y)*256 + i*4 + a])
    const int t = threadIdx.x;        // k = j*4 + a
    const int y = blockIdx.x;         // 0..63
    const int j = t >> 2, a = t & 3;
    for (int i = 0; i < 64; ++i) {
        const float v = c1[(size_t)(j * 64 + y) * 256 + i * 4 + a];
        c1t[((size_t)y * 64 + i) * 256 + t] = f2bf(v);
    }
}

// ---------------- main kernel ----------------
__global__ __launch_bounds__(512, 4) void btt_main(
    const float* __restrict__ x,        // (8192, 4096) f32
    const ushort_t* __restrict__ c0t,   // [c(256)][u(4096)] bf16
    const ushort_t* __restrict__ c1t,   // [y(64)][i(64)][k(256)] bf16
    const float* __restrict__ bias,     // (4096) f32
    float* __restrict__ out)            // (8192, 4096) f32
{
    // z1[b(32)][byte (ii*64 + k*2) ^ ((b&7)<<4)] : 16 KB
    __shared__ __align__(16) char z1[32 * 512];

    const int t    = threadIdx.x;
    const int w    = t >> 6;          // wave 0..7
    const int lane = t & 63;
    const int quad = lane >> 4;
    const int l16  = lane & 15;

    const int b0 = blockIdx.x * 32;
    const int i0 = blockIdx.y * 8;

    const int mb = w >> 2;            // stage-2 b-tile (0..1)
    const int yq = w & 3;             // stage-2 y-quarter (0..3)
    const int y  = yq * 16 + l16;

    // acc[ii]: out(b = mb*16 + quad*4 + reg, y, i0+ii)
    f32x4 acc[8];
#pragma unroll
    for (int ii = 0; ii < 8; ++ii) {
        const float bv = bias[y * 64 + i0 + ii];
        acc[ii] = (f32x4){bv, bv, bv, bv};
    }

    const ushort_t* aptr = c0t + (size_t)(i0 * 4 + l16) * 4096 + quad * 8;
    const float*    xptr = x   + (size_t)(b0 + l16) * 4096 + quad * 8;
    const ushort_t* bzp  = c1t + ((size_t)y * 64 + i0) * 256 + quad * 8;

#pragma unroll 1
    for (int g = 0; g < 8; ++g) {
        const int j  = g * 8 + w;
        const int jc = j * 64;

        // ---- stage-1 fragments: all loads issued up front ----
        sfrag8 A[2][2];   // c0t: A[m=col][k=u], lane m=l16
#pragma unroll
        for (int nt = 0; nt < 2; ++nt)
#pragma unroll
            for (int kh = 0; kh < 2; ++kh)
                A[nt][kh] = *(const sfrag8*)(aptr + (size_t)nt * 16 * 4096 + jc + kh * 32);

        sfrag8 Bf[2][2];  // X: B[k=u][n=b], lane n=l16
#pragma unroll
        for (int bt = 0; bt < 2; ++bt)
#pragma unroll
            for (int kh = 0; kh < 2; ++kh) {
                const float* p = xptr + (size_t)bt * 16 * 4096 + jc + kh * 32;
                const float4 v0 = *(const float4*)p;
                const float4 v1 = *(const float4*)(p + 4);
                sfrag8 pk;
                pk[0] = (short)f2bf(v0.x); pk[1] = (short)f2bf(v0.y);
                pk[2] = (short)f2bf(v0.z); pk[3] = (short)f2bf(v0.w);
                pk[4] = (short)f2bf(v1.x); pk[5] = (short)f2bf(v1.y);
                pk[6] = (short)f2bf(v1.z); pk[7] = (short)f2bf(v1.w);
                Bf[bt][kh] = pk;
            }

        // ---- stage-1 MFMAs (swapped): D[col][b], col = nt*16+quad*4+reg ----
#pragma unroll
        for (int nt = 0; nt < 2; ++nt)
#pragma unroll
            for (int bt = 0; bt < 2; ++bt) {
                f32x4 d = {0.f, 0.f, 0.f, 0.f};
                d = __builtin_amdgcn_mfma_f32_16x16x32_bf16(A[nt][0], Bf[bt][0], d, 0, 0, 0);
                d = __builtin_amdgcn_mfma_f32_16x16x32_bf16(A[nt][1], Bf[bt][1], d, 0, 0, 0);
                const int bb = bt * 16 + l16;          // b row
                const int ii = nt * 4 + quad;          // i-local
                // k = w*4 + reg (reg = a): one 8B packed store
                const ushort4 pk = make_ushort4(f2bf(d[0]), f2bf(d[1]),
                                                f2bf(d[2]), f2bf(d[3]));
                *(ushort4*)(z1 + bb * 512 + ((ii * 64 + w * 8) ^ ((bb & 7) << 4))) = pk;
            }

        __syncthreads();   // z1 visible

        // ---- stage 2: bz direct from global (L2-hot), az from LDS ----
        sfrag8 bz[8];
#pragma unroll
        for (int ii = 0; ii < 8; ++ii)
            bz[ii] = *(const sfrag8*)(bzp + ii * 256 + g * 32);

        const int ar = mb * 16 + l16;
        const int as = (ar & 7) << 4;
#pragma unroll
        for (int ii = 0; ii < 8; ++ii) {
            const sfrag8 az = *(const sfrag8*)(z1 + ar * 512
                                               + ((ii * 64 + quad * 16) ^ as));
            acc[ii] = __builtin_amdgcn_mfma_f32_16x16x32_bf16(az, bz[ii], acc[ii], 0, 0, 0);
        }

        __syncthreads();   // z1 readers done before next g's writes
    }

    // ---- epilogue ----
#pragma unroll
    for (int reg = 0; reg < 4; ++reg) {
        const int bb = mb * 16 + quad * 4 + reg;
        float* dst = out + (size_t)(b0 + bb) * 4096 + y * 64 + i0;
        *(float4*)dst       = make_float4(acc[0][reg], acc[1][reg],
                                          acc[2][reg], acc[3][reg]);
        *(float4*)(dst + 4) = make_float4(acc[4][reg], acc[5][reg],
                                          acc[6][reg], acc[7][reg]);
    }
}

extern "C" void kernel_launch(void* const* d_in, const int* in_sizes, int n_in,
                              void* d_out, int out_size, void* d_ws, size_t ws_size,
                              hipStream_t stream) {
    const float* x     = (const float*)d_in[0];
    const float* core0 = (const float*)d_in[1];
    const float* core1 = (const float*)d_in[2];
    const float* bias  = (const float*)d_in[3];
    float* out = (float*)d_out;

    // workspace layout: [0,2MB) c0t ; [2MB,4MB) c1t  (needs ws_size >= 4MB)
    ushort_t* c0t = (ushort_t*)d_ws;
    ushort_t* c1t = (ushort_t*)d_ws + (size_t)256 * 4096;

    prep_c0t<<<dim3(64, 4), 256, 0, stream>>>(core0, c0t);
    prep_c1t<<<dim3(64), 256, 0, stream>>>(core1, c1t);

    dim3 grid(8192 / 32, 64 / 8);   // (256, 8)
    btt_main<<<grid, 512, 0, stream>>>(x, c0t, c1t, bias, out);
}

// Round 3
// 520.007 us; speedup vs baseline: 1.1897x; 1.0300x over previous
//
#include <hip/hip_runtime.h>

// BTT fused MFMA kernel (round 7): traffic fix.
//   - grid swapped to (i fastest, b outer): 8 sibling i-blocks of a b-tile are
//     consecutive -> co-resident on the 8 XCDs -> X shared via L3 (one HBM
//     fetch instead of 4.3x). gridDim.x == 8 == NXCD also pins each i0's
//     c0t/c1t slices to one XCD's L2.
//   - prep_c1t rewritten: 512 blocks, coalesced float4 reads (was 64 blocks,
//     strided scalar, ~100us).
//   - stage-2 c1t fragment loads hoisted above stage-1 MFMAs (latency hidden
//     under compute; vmcnt leaves them in flight).
//
// out[b, y*64+i] = bias[y*64+i]
//   + sum_{j,a} ( sum_u X[b,j*64+u] * core0[(j*64+u)*256 + i*4+a] )
//               * core1[(j*64+y)*256 + i*4 + a]
//
// MFMA 16x16x32 bf16 layouts (HW-verified):
//   A[m][k]: m=lane&15, k=(lane>>4)*8+j ; B[k][n]: n=lane&15, k=(lane>>4)*8+j
//   D[m][n]: n=lane&15, m=(lane>>4)*4+reg

typedef unsigned short ushort_t;
typedef __attribute__((ext_vector_type(8))) short sfrag8;   // 8 bf16
typedef __attribute__((ext_vector_type(4))) float f32x4;

__device__ inline ushort_t f2bf(float f) {
    unsigned int u = __builtin_bit_cast(unsigned int, f);
    u += 0x7fffu + ((u >> 16) & 1u);   // RNE
    return (ushort_t)(u >> 16);
}

// ---------------- prep kernels ----------------
__global__ __launch_bounds__(256) void prep_c0t(const float* __restrict__ c0,
                                                ushort_t* __restrict__ c0t) {
    // c0t[c][u] = bf16(core0[u*256 + c]) ; tiled 64x64 transpose
    __shared__ float tile[64][65];
    const int t = threadIdx.x;
    const int ub = blockIdx.x * 64;   // u block: 4096/64 = 64
    const int cb = blockIdx.y * 64;   // c block: 256/64  = 4
#pragma unroll
    for (int it = 0; it < 16; ++it) {
        const int r = it * 4 + (t >> 6);
        const int c = t & 63;
        tile[r][c] = c0[(size_t)(ub + r) * 256 + cb + c];
    }
    __syncthreads();
#pragma unroll
    for (int it = 0; it < 16; ++it) {
        const int r = it * 4 + (t >> 6);   // c-local row
        const int c = t & 63;              // u-local col
        c0t[(size_t)(cb + r) * 4096 + ub + c] = f2bf(tile[c][r]);
    }
}

__global__ __launch_bounds__(256) void prep_c1t(const float* __restrict__ c1,
                                                ushort_t* __restrict__ c1t) {
    // c1t[(y*64 + i)*256 + j*4 + a] = bf16(core1[(j*64+y)*256 + i*4 + a])
    // block (y, jg): reads 8 rows of c1 (coalesced float4), writes ushort4.
    const int y  = blockIdx.x;        // 0..63
    const int jg = blockIdx.y;        // 0..7
    const int t  = threadIdx.x;
#pragma unroll
    for (int iter = 0; iter < 2; ++iter) {
        const int idx = iter * 256 + t;      // 0..511
        const int jj  = idx >> 6;            // 0..7
        const int i   = idx & 63;
        const int j   = jg * 8 + jj;
        const float4 v = *(const float4*)(c1 + (size_t)(j * 64 + y) * 256 + i * 4);
        const ushort4 pk = make_ushort4(f2bf(v.x), f2bf(v.y), f2bf(v.z), f2bf(v.w));
        *(ushort4*)(c1t + ((size_t)y * 64 + i) * 256 + j * 4) = pk;
    }
}

// ---------------- main kernel ----------------
__global__ __launch_bounds__(512, 4) void btt_main(
    const float* __restrict__ x,        // (8192, 4096) f32
    const ushort_t* __restrict__ c0t,   // [c(256)][u(4096)] bf16
    const ushort_t* __restrict__ c1t,   // [y(64)][i(64)][k(256)] bf16
    const float* __restrict__ bias,     // (4096) f32
    float* __restrict__ out)            // (8192, 4096) f32
{
    // z1[b(32)][byte (ii*64 + k*2) ^ ((b&7)<<4)] : 16 KB
    __shared__ __align__(16) char z1[32 * 512];

    const int t    = threadIdx.x;
    const int w    = t >> 6;          // wave 0..7
    const int lane = t & 63;
    const int quad = lane >> 4;
    const int l16  = lane & 15;

    const int i0 = blockIdx.x * 8;    // i fastest: siblings share b-tile
    const int b0 = blockIdx.y * 32;

    const int mb = w >> 2;            // stage-2 b-tile (0..1)
    const int yq = w & 3;             // stage-2 y-quarter (0..3)
    const int y  = yq * 16 + l16;

    // acc[ii]: out(b = mb*16 + quad*4 + reg, y, i0+ii)
    f32x4 acc[8];
#pragma unroll
    for (int ii = 0; ii < 8; ++ii) {
        const float bv = bias[y * 64 + i0 + ii];
        acc[ii] = (f32x4){bv, bv, bv, bv};
    }

    const ushort_t* aptr = c0t + (size_t)(i0 * 4 + l16) * 4096 + quad * 8;
    const float*    xptr = x   + (size_t)(b0 + l16) * 4096 + quad * 8;
    const ushort_t* bzp  = c1t + ((size_t)y * 64 + i0) * 256 + quad * 8;

#pragma unroll 1
    for (int g = 0; g < 8; ++g) {
        const int jc = (g * 8 + w) * 64;   // wave's j-column base

        // ---- stage-1 fragments: all loads issued up front ----
        sfrag8 A[2][2];   // c0t: A[m=col][k=u], lane m=l16
#pragma unroll
        for (int nt = 0; nt < 2; ++nt)
#pragma unroll
            for (int kh = 0; kh < 2; ++kh)
                A[nt][kh] = *(const sfrag8*)(aptr + (size_t)nt * 16 * 4096 + jc + kh * 32);

        sfrag8 Bf[2][2];  // X: B[k=u][n=b], lane n=l16
#pragma unroll
        for (int bt = 0; bt < 2; ++bt)
#pragma unroll
            for (int kh = 0; kh < 2; ++kh) {
                const float* p = xptr + (size_t)bt * 16 * 4096 + jc + kh * 32;
                const float4 v0 = *(const float4*)p;
                const float4 v1 = *(const float4*)(p + 4);
                sfrag8 pk;
                pk[0] = (short)f2bf(v0.x); pk[1] = (short)f2bf(v0.y);
                pk[2] = (short)f2bf(v0.z); pk[3] = (short)f2bf(v0.w);
                pk[4] = (short)f2bf(v1.x); pk[5] = (short)f2bf(v1.y);
                pk[6] = (short)f2bf(v1.z); pk[7] = (short)f2bf(v1.w);
                Bf[bt][kh] = pk;
            }

        // ---- stage-2 c1t fragments: issue now, consume after barrier ----
        sfrag8 bz[8];
#pragma unroll
        for (int ii = 0; ii < 8; ++ii)
            bz[ii] = *(const sfrag8*)(bzp + ii * 256 + g * 32);

        // ---- stage-1 MFMAs (swapped): D[col][b], col = nt*16+quad*4+reg ----
#pragma unroll
        for (int nt = 0; nt < 2; ++nt)
#pragma unroll
            for (int bt = 0; bt < 2; ++bt) {
                f32x4 d = {0.f, 0.f, 0.f, 0.f};
                d = __builtin_amdgcn_mfma_f32_16x16x32_bf16(A[nt][0], Bf[bt][0], d, 0, 0, 0);
                d = __builtin_amdgcn_mfma_f32_16x16x32_bf16(A[nt][1], Bf[bt][1], d, 0, 0, 0);
                const int bb = bt * 16 + l16;          // b row
                const int ii = nt * 4 + quad;          // i-local
                // k = w*4 + reg (reg = a): one 8B packed store
                const ushort4 pk = make_ushort4(f2bf(d[0]), f2bf(d[1]),
                                                f2bf(d[2]), f2bf(d[3]));
                *(ushort4*)(z1 + bb * 512 + ((ii * 64 + w * 8) ^ ((bb & 7) << 4))) = pk;
            }

        __syncthreads();   // z1 visible

        // ---- stage 2: az from z1 LDS, bz already in regs ----
        const int ar = mb * 16 + l16;
        const int as = (ar & 7) << 4;
#pragma unroll
        for (int ii = 0; ii < 8; ++ii) {
            const sfrag8 az = *(const sfrag8*)(z1 + ar * 512
                                               + ((ii * 64 + quad * 16) ^ as));
            acc[ii] = __builtin_amdgcn_mfma_f32_16x16x32_bf16(az, bz[ii], acc[ii], 0, 0, 0);
        }

        __syncthreads();   // z1 readers done before next g's writes
    }

    // ---- epilogue ----
#pragma unroll
    for (int reg = 0; reg < 4; ++reg) {
        const int bb = mb * 16 + quad * 4 + reg;
        float* dst = out + (size_t)(b0 + bb) * 4096 + y * 64 + i0;
        *(float4*)dst       = make_float4(acc[0][reg], acc[1][reg],
                                          acc[2][reg], acc[3][reg]);
        *(float4*)(dst + 4) = make_float4(acc[4][reg], acc[5][reg],
                                          acc[6][reg], acc[7][reg]);
    }
}

extern "C" void kernel_launch(void* const* d_in, const int* in_sizes, int n_in,
                              void* d_out, int out_size, void* d_ws, size_t ws_size,
                              hipStream_t stream) {
    const float* x     = (const float*)d_in[0];
    const float* core0 = (const float*)d_in[1];
    const float* core1 = (const float*)d_in[2];
    const float* bias  = (const float*)d_in[3];
    float* out = (float*)d_out;

    // workspace layout: [0,2MB) c0t ; [2MB,4MB) c1t  (needs ws_size >= 4MB)
    ushort_t* c0t = (ushort_t*)d_ws;
    ushort_t* c1t = (ushort_t*)d_ws + (size_t)256 * 4096;

    prep_c0t<<<dim3(64, 4), 256, 0, stream>>>(core0, c0t);
    prep_c1t<<<dim3(64, 8), 256, 0, stream>>>(core1, c1t);

    dim3 grid(64 / 8, 8192 / 32);   // (8, 256): i fastest
    btt_main<<<grid, 512, 0, stream>>>(x, c0t, c1t, bias, out);
}

// Round 4
// 461.319 us; speedup vs baseline: 1.3410x; 1.1272x over previous
//
#include <hip/hip_runtime.h>

// BTT fused MFMA kernel (round 8): coalesced X staging + raw-barrier pipeline.
//
// out[b, y*64+i] = bias[y*64+i]
//   + sum_{j,a} ( sum_u X[b,j*64+u] * core0[(j*64+u)*256 + i*4+a] )
//               * core1[(j*64+y)*256 + i*4 + a]
//
// Per block (b-tile 32, i-tile 8), per g (8 j's):
//   A: cvt+ds_write X(g) tile (32x512 bf16, XOR-swizzled), issue c0t frags,
//      issue X(g+1) f32 loads (stay in flight across barriers);  bar1
//   B: stage-1: Xfrags via ds_read_b128, 8 MFMA -> z1 (swizzled), issue c1t
//      frags;                                                    bar2
//   C: stage-2: az via ds_read_b128, 8 MFMA into acc;            bar3
// Raw barriers (lgkmcnt(0) + s_barrier) so vmcnt prefetches survive.
//
// XCD swizzle: XCD k (= bid&7) owns b in [k*1024,(k+1)*1024), i fastest ->
// X streamed through each XCD's L2 once (16 MB instead of 128 MB).
//
// MFMA 16x16x32 bf16 layouts (HW-verified):
//   A[m][k]: m=lane&15, k=(lane>>4)*8+j ; B[k][n]: n=lane&15, k=(lane>>4)*8+j
//   D[m][n]: n=lane&15, m=(lane>>4)*4+reg

typedef unsigned short ushort_t;
typedef __attribute__((ext_vector_type(8))) short sfrag8;   // 8 bf16
typedef __attribute__((ext_vector_type(4))) float f32x4;

__device__ inline ushort_t f2bf(float f) {
    unsigned int u = __builtin_bit_cast(unsigned int, f);
    u += 0x7fffu + ((u >> 16) & 1u);   // RNE
    return (ushort_t)(u >> 16);
}

// raw barrier: drain LDS (cross-wave visibility) but leave vmcnt in flight
#define BARRIER() do {                                     \
    asm volatile("s_waitcnt lgkmcnt(0)" ::: "memory");     \
    __builtin_amdgcn_s_barrier();                          \
    asm volatile("" ::: "memory");                         \
} while (0)

// ---------------- prep kernels (unchanged, verified) ----------------
__global__ __launch_bounds__(256) void prep_c0t(const float* __restrict__ c0,
                                                ushort_t* __restrict__ c0t) {
    // c0t[c][u] = bf16(core0[u*256 + c]) ; tiled 64x64 transpose
    __shared__ float tile[64][65];
    const int t = threadIdx.x;
    const int ub = blockIdx.x * 64;
    const int cb = blockIdx.y * 64;
#pragma unroll
    for (int it = 0; it < 16; ++it) {
        const int r = it * 4 + (t >> 6);
        const int c = t & 63;
        tile[r][c] = c0[(size_t)(ub + r) * 256 + cb + c];
    }
    __syncthreads();
#pragma unroll
    for (int it = 0; it < 16; ++it) {
        const int r = it * 4 + (t >> 6);
        const int c = t & 63;
        c0t[(size_t)(cb + r) * 4096 + ub + c] = f2bf(tile[c][r]);
    }
}

__global__ __launch_bounds__(256) void prep_c1t(const float* __restrict__ c1,
                                                ushort_t* __restrict__ c1t) {
    // c1t[(y*64 + i)*256 + j*4 + a] = bf16(core1[(j*64+y)*256 + i*4 + a])
    const int y  = blockIdx.x;
    const int jg = blockIdx.y;
    const int t  = threadIdx.x;
#pragma unroll
    for (int iter = 0; iter < 2; ++iter) {
        const int idx = iter * 256 + t;
        const int jj  = idx >> 6;
        const int i   = idx & 63;
        const int j   = jg * 8 + jj;
        const float4 v = *(const float4*)(c1 + (size_t)(j * 64 + y) * 256 + i * 4);
        const ushort4 pk = make_ushort4(f2bf(v.x), f2bf(v.y), f2bf(v.z), f2bf(v.w));
        *(ushort4*)(c1t + ((size_t)y * 64 + i) * 256 + j * 4) = pk;
    }
}

// ---------------- main kernel ----------------
__global__ __launch_bounds__(512, 4) void btt_main(
    const float* __restrict__ x,        // (8192, 4096) f32
    const ushort_t* __restrict__ c0t,   // [c(256)][u(4096)] bf16
    const ushort_t* __restrict__ c1t,   // [y(64)][i(64)][k(256)] bf16
    const float* __restrict__ bias,     // (4096) f32
    float* __restrict__ out)            // (8192, 4096) f32
{
    // xlds[b(32)][byte u*2 ^ ((b&7)<<4)] : 32 KB   (one g-group of X, bf16)
    // z1  [b(32)][byte (ii*64+k*2) ^ ((b&7)<<4)] : 16 KB
    __shared__ __align__(16) char xlds[32 * 1024];
    __shared__ __align__(16) char z1[32 * 512];

    const int t    = threadIdx.x;
    const int w    = t >> 6;          // wave 0..7
    const int lane = t & 63;
    const int quad = lane >> 4;
    const int l16  = lane & 15;

    // XCD-partitioned swizzle: xcd owns b-range, i fastest within
    const int bid = blockIdx.x;
    const int xcd = bid & 7;
    const int idx = bid >> 3;                 // 0..255
    const int b0  = xcd * 1024 + (idx >> 3) * 32;
    const int i0  = (idx & 7) * 8;

    const int mb = w >> 2;            // stage-2 b-tile (0..1)
    const int yq = w & 3;             // stage-2 y-quarter (0..3)
    const int y  = yq * 16 + l16;

    // acc[ii]: out(b = mb*16 + quad*4 + reg, y, i0+ii)
    f32x4 acc[8];
#pragma unroll
    for (int ii = 0; ii < 8; ++ii) {
        const float bv = bias[y * 64 + i0 + ii];
        acc[ii] = (f32x4){bv, bv, bv, bv};
    }

    const ushort_t* aptr = c0t + (size_t)(i0 * 4 + l16) * 4096 + quad * 8;
    const ushort_t* bzp  = c1t + ((size_t)y * 64 + i0) * 256 + quad * 8;
    // X staging: thread covers rows c*8+w, cols h*256 + lane*4 (+3), per g
    const float* xsrc = x + (size_t)(b0 + w) * 4096 + lane * 4;

    // ---- prologue: issue X(0) loads ----
    float4 xr[8];
#pragma unroll
    for (int c = 0; c < 4; ++c)
#pragma unroll
        for (int h = 0; h < 2; ++h)
            xr[c * 2 + h] = *(const float4*)(xsrc + (size_t)c * 8 * 4096 + h * 256);

#pragma unroll 1
    for (int g = 0; g < 8; ++g) {
        const int jc = (g * 8 + w) * 64;   // wave's j-column base

        // ======== PHASE A: stage X(g) into LDS ========
#pragma unroll
        for (int c = 0; c < 4; ++c)
#pragma unroll
            for (int h = 0; h < 2; ++h) {
                const float4 v = xr[c * 2 + h];
                const ushort4 pk = make_ushort4(f2bf(v.x), f2bf(v.y),
                                                f2bf(v.z), f2bf(v.w));
                // row = c*8+w (row&7 == w), byte = (h*256+lane*4)*2
                *(ushort4*)(xlds + (c * 8 + w) * 1024
                            + ((h * 512 + lane * 8) ^ (w << 4))) = pk;
            }

        // issue c0t frags for this g (L2-hot, consumed in B)
        sfrag8 A[2][2];
#pragma unroll
        for (int nt = 0; nt < 2; ++nt)
#pragma unroll
            for (int kh = 0; kh < 2; ++kh)
                A[nt][kh] = *(const sfrag8*)(aptr + (size_t)nt * 16 * 4096 + jc + kh * 32);

        // issue X(g+1) loads: stay in flight across the barriers below
        if (g != 7) {
#pragma unroll
            for (int c = 0; c < 4; ++c)
#pragma unroll
                for (int h = 0; h < 2; ++h)
                    xr[c * 2 + h] = *(const float4*)(xsrc + (size_t)c * 8 * 4096
                                                     + (g + 1) * 512 + h * 256);
        }

        BARRIER();   // bar1: xlds visible

        // ======== PHASE B: stage-1 MFMAs -> z1 ========
        {
            sfrag8 Bf[2][2];   // X frags from LDS: B[k=u][n=b]
#pragma unroll
            for (int bt = 0; bt < 2; ++bt)
#pragma unroll
                for (int kh = 0; kh < 2; ++kh)
                    Bf[bt][kh] = *(const sfrag8*)(xlds + (bt * 16 + l16) * 1024
                                  + ((w * 128 + kh * 64 + quad * 16) ^ ((l16 & 7) << 4)));

#pragma unroll
            for (int nt = 0; nt < 2; ++nt)
#pragma unroll
                for (int bt = 0; bt < 2; ++bt) {
                    f32x4 d = {0.f, 0.f, 0.f, 0.f};
                    d = __builtin_amdgcn_mfma_f32_16x16x32_bf16(A[nt][0], Bf[bt][0], d, 0, 0, 0);
                    d = __builtin_amdgcn_mfma_f32_16x16x32_bf16(A[nt][1], Bf[bt][1], d, 0, 0, 0);
                    const int bb = bt * 16 + l16;          // b row
                    const int ii = nt * 4 + quad;          // i-local
                    const ushort4 pk = make_ushort4(f2bf(d[0]), f2bf(d[1]),
                                                    f2bf(d[2]), f2bf(d[3]));
                    *(ushort4*)(z1 + bb * 512 + ((ii * 64 + w * 8) ^ ((bb & 7) << 4))) = pk;
                }
        }

        // issue c1t frags (consumed in C after bar2; A/Bf regs dead by now)
        sfrag8 bz[8];
#pragma unroll
        for (int ii = 0; ii < 8; ++ii)
            bz[ii] = *(const sfrag8*)(bzp + ii * 256 + g * 32);

        BARRIER();   // bar2: z1 visible

        // ======== PHASE C: stage-2 MFMAs into acc ========
        {
            const int ar = mb * 16 + l16;
            const int as = (ar & 7) << 4;
#pragma unroll
            for (int ii = 0; ii < 8; ++ii) {
                const sfrag8 az = *(const sfrag8*)(z1 + ar * 512
                                                   + ((ii * 64 + quad * 16) ^ as));
                acc[ii] = __builtin_amdgcn_mfma_f32_16x16x32_bf16(az, bz[ii], acc[ii], 0, 0, 0);
            }
        }

        BARRIER();   // bar3: z1/xlds readers done before next g's writes
    }

    // ---- epilogue ----
#pragma unroll
    for (int reg = 0; reg < 4; ++reg) {
        const int bb = mb * 16 + quad * 4 + reg;
        float* dst = out + (size_t)(b0 + bb) * 4096 + y * 64 + i0;
        *(float4*)dst       = make_float4(acc[0][reg], acc[1][reg],
                                          acc[2][reg], acc[3][reg]);
        *(float4*)(dst + 4) = make_float4(acc[4][reg], acc[5][reg],
                                          acc[6][reg], acc[7][reg]);
    }
}

extern "C" void kernel_launch(void* const* d_in, const int* in_sizes, int n_in,
                              void* d_out, int out_size, void* d_ws, size_t ws_size,
                              hipStream_t stream) {
    const float* x     = (const float*)d_in[0];
    const float* core0 = (const float*)d_in[1];
    const float* core1 = (const float*)d_in[2];
    const float* bias  = (const float*)d_in[3];
    float* out = (float*)d_out;

    // workspace layout: [0,2MB) c0t ; [2MB,4MB) c1t  (needs ws_size >= 4MB)
    ushort_t* c0t = (ushort_t*)d_ws;
    ushort_t* c1t = (ushort_t*)d_ws + (size_t)256 * 4096;

    prep_c0t<<<dim3(64, 4), 256, 0, stream>>>(core0, c0t);
    prep_c1t<<<dim3(64, 8), 256, 0, stream>>>(core1, c1t);

    btt_main<<<dim3(2048), 512, 0, stream>>>(x, c0t, c1t, bias, out);
}